// Round 4
// baseline (2427.059 us; speedup 1.0000x reference)
//
#include <hip/hip_runtime.h>
#include <stdint.h>

#define T_STEPS 512
#define B_ALL   512
#define SDIM    64
#define HID     128
#define ADIM    10
#define CB      32      // batch rows per chunk
#define NSLOT   4       // h buffer depth (anti-deps at t-3)

typedef __attribute__((ext_vector_type(4))) float f32x4;
typedef __attribute__((ext_vector_type(8))) short s16x8;

#define MFMA(a,b,c) __builtin_amdgcn_mfma_f32_16x16x32_bf16(a,b,c,0,0,0)
#define SC_AGENT __HIP_MEMORY_SCOPE_AGENT

__device__ __forceinline__ unsigned short bf_rne(float f){
    union{float f; unsigned int u;} v; v.f = f;
    unsigned int r = v.u + 0x7fffu + ((v.u >> 16) & 1u);
    return (unsigned short)(r >> 16);
}
__device__ __forceinline__ float us_to_f(unsigned short h){
    union{unsigned int u; float f;} v; v.u = ((unsigned int)h) << 16; return v.f;
}
__device__ __forceinline__ void split_pair(float f, unsigned short& hi, unsigned short& lo){
    hi = bf_rne(f);
    lo = bf_rne(f - us_to_f(hi));
}
__device__ __forceinline__ void load_split8(const float* p, s16x8& h, s16x8& l){
#pragma unroll
    for (int i = 0; i < 8; i++){
        unsigned short a, b; split_pair(p[i], a, b);
        h[i] = (short)a; l[i] = (short)b;
    }
}
__device__ __forceinline__ float sigm(float x){ return 1.f / (1.f + __expf(-x)); }
__device__ __forceinline__ float tanh_f(float x){ return 1.f - 2.f / (__expf(2.f * x) + 1.f); }

// ---- cross-WG protocol, SELF-TAGGED DATA edition ----
// Every packed h word (hi16|lo16) donates the 2 LSBs of lo to a per-word
// epoch tag = ((t>>2)+1)&3. Properties:
//  * consecutive writes to the same slot (t, t+4) get distinct tags;
//  * tag 0 is reserved for "never written" (memset), since ((t>>2)+1)&3==0
//    first occurs at t>=12, by which time the slot was re-written with tag!=0.
// Consumers spin directly on the data words, checking all tags — the poll IS
// the data load (one coherence-point hop). Each h word is a 4B atomic store:
// no torn-write risk, no ordering assumption, no producer drain, no forward
// watermark. Data perturbation from losing lo's 2 LSBs: <= 3*2^-8*|lo|
// <= 2.3e-5*|h| — negligible.
// The ONLY watermark left is the backward anti-dep (layer-0 must not
// overwrite h0(t-4) before layer-1 finished reading h0(t-4)); it carries
// read-progress semantics, so a plain relaxed store with NO drain suffices.
__device__ __forceinline__ uint32_t tag_of(int t){ return (uint32_t)(((t >> 2) + 1) & 3); }

__device__ __forceinline__ void wait_wm(const uint32_t* wm, uint32_t v, uint32_t& seen, int lane15){
    if (seen >= v) return;                      // monotone shadow: skip poll when known-satisfied
    const uint32_t* p = wm + (size_t)lane15 * 16;   // 64B stride
    for (;;){
        uint32_t c = __hip_atomic_load(p, __ATOMIC_RELAXED, SC_AGENT);
        uint32_t m = c;
#pragma unroll
        for (int off = 8; off; off >>= 1){
            uint32_t o = (uint32_t)__shfl_xor((int)m, off, 16);
            m = m < o ? m : o;                  // min over the 16-slot group
        }
        if (m >= v){ seen = m; break; }         // cache true min: future waits may skip
        __builtin_amdgcn_s_sleep(1);
    }
    __asm__ volatile("" ::: "memory");
}
__device__ __forceinline__ void wm_publish_nd(uint32_t* wm, int slot, uint32_t val){
    __hip_atomic_store(wm + (size_t)slot * 16, val, __ATOMIC_RELAXED, SC_AGENT);
}
__device__ __forceinline__ void h_store(uint32_t* p, uint32_t v){
    __hip_atomic_store(p, v, __ATOMIC_RELAXED, SC_AGENT);     // write-through sc1
}
// Spin-load N frag-pairs (8 u32 each, stride in u32) until every word's
// 2-bit tag equals e, then unpack to hi/lo bf16 fragments.
template<int N>
__device__ __forceinline__ void spin_frags(const uint32_t* p0, int stride, uint32_t e,
                                           s16x8* ah, s16x8* al)
{
    unsigned long long w[N][4];
    for (;;){
#pragma unroll
        for (int i = 0; i < N; i++)
#pragma unroll
            for (int j = 0; j < 4; j++)
                w[i][j] = __hip_atomic_load(
                    (const unsigned long long*)(p0 + (size_t)i * stride) + j,
                    __ATOMIC_RELAXED, SC_AGENT);
        uint32_t bad = 0;
#pragma unroll
        for (int i = 0; i < N; i++)
#pragma unroll
            for (int j = 0; j < 4; j++){
                uint32_t a = (uint32_t)w[i][j], b = (uint32_t)(w[i][j] >> 32);
                bad |= ((a ^ e) & 3u) | ((b ^ e) & 3u);
            }
        if (__all(bad == 0)) break;
        __builtin_amdgcn_s_sleep(1);
    }
#pragma unroll
    for (int i = 0; i < N; i++)
#pragma unroll
        for (int j = 0; j < 4; j++){
            uint32_t a = (uint32_t)w[i][j], b = (uint32_t)(w[i][j] >> 32);
            ah[i][2*j]   = (short)(a >> 16); al[i][2*j]   = (short)(a & 0xffffu);
            ah[i][2*j+1] = (short)(b >> 16); al[i][2*j+1] = (short)(b & 0xffffu);
        }
}
__device__ __forceinline__ void zero_frags(s16x8* ah, s16x8* al, int n){
    for (int i = 0; i < n; i++){
#pragma unroll
        for (int j = 0; j < 8; j++){ ah[i][j] = 0; al[i][j] = 0; }
    }
}

__global__ void __launch_bounds__(256, 1)
lstm_fused(const float* __restrict__ x,
           const float* __restrict__ Wih0, const float* __restrict__ Whh0,
           const float* __restrict__ bih0, const float* __restrict__ bhh0,
           const float* __restrict__ Wih1, const float* __restrict__ Whh1,
           const float* __restrict__ bih1, const float* __restrict__ bhh1,
           const float* __restrict__ Wout, const float* __restrict__ bout,
           float* __restrict__ out, unsigned char* __restrict__ ws)
{
    extern __shared__ char smem[];
    float* part = (float*)smem;                      // 8 slots * 256 f32 = 8 KB

    const int tid  = threadIdx.x;
    const int wave = tid >> 6, lane = tid & 63;
    const int lm = lane & 15, lq = lane >> 4;
    const int mt = wave & 1, kh = wave >> 1;

    const int wg = blockIdx.x;
    const int chunk = wg >> 4, sub = wg & 15;
    const int layer = sub >> 3, slice = sub & 7;
    const int b0 = chunk * CB;

    // ws layout: [0,16KB) wm1 (16 chunks x 16 slots x 64B) — layer-1 progress,
    //            [16KB,...) h0/h1 packed (hi|lo|tag2) u32 buffers
    uint32_t* wm1 = (uint32_t*)(ws + (size_t)chunk * 1024);
    uint32_t* h0p = (uint32_t*)(ws + 16384);                 // [NSLOT][512][128]
    uint32_t* h1p = h0p + (size_t)NSLOT * B_ALL * HID;

    uint32_t seen1 = 0;                                      // wm1 min shadow

    if (layer == 0){
        // ---- layer 0: gates = x @ Wih0^T + h0(t-1) @ Whh0^T ----
        // K = 64 (x: kt 0,1) + 128 (h0: kt 2..5); kh=0 -> kt{0,1,2}, kh=1 -> kt{3,4,5}
        s16x8 wh[4][3], wl[4][3];
#pragma unroll
        for (int g = 0; g < 4; g++)
#pragma unroll
            for (int ktl = 0; ktl < 3; ktl++){
                int kt = kh * 3 + ktl;
                int j = g * HID + slice * 16 + lm;
                const float* src = (kt < 2) ? (Wih0 + (size_t)j * SDIM + kt * 32 + lq * 8)
                                            : (Whh0 + (size_t)j * HID + (kt - 2) * 32 + lq * 8);
                load_split8(src, wh[g][ktl], wl[g][ktl]);
            }
        float bias[4];
#pragma unroll
        for (int g = 0; g < 4; g++){
            int j = g * HID + slice * 16 + lm;
            bias[g] = bih0[j] + bhh0[j];
        }
        float cst[4] = {0.f, 0.f, 0.f, 0.f};

        for (int t = 0; t < T_STEPS; t++){
            // x(t) is dependency-free: load+split before any spin
            s16x8 Ah[3], Al[3];
            if (kh == 0){
                const float* xp = x + ((size_t)t * B_ALL + b0 + mt * 16 + lm) * SDIM;
                float v[16];
#pragma unroll
                for (int kt = 0; kt < 2; kt++)
#pragma unroll
                    for (int j = 0; j < 8; j++) v[kt * 8 + j] = xp[kt * 32 + lq * 8 + j];
#pragma unroll
                for (int kt = 0; kt < 2; kt++)
#pragma unroll
                    for (int j = 0; j < 8; j++){
                        unsigned short hh, ll; split_pair(v[kt * 8 + j], hh, ll);
                        Ah[kt][j] = (short)hh; Al[kt][j] = (short)ll;
                    }
            }
            // backward anti-dep only: layer-1 must have consumed h0(t-4)
            if (t > 3) wait_wm(wm1, (uint32_t)(t - 3), seen1, lm);

            const uint32_t* hr = h0p + ((size_t)((t - 1) & 3) * B_ALL + b0 + mt * 16 + lm) * HID;
            if (t == 0){
                if (kh == 0) zero_frags(&Ah[2], &Al[2], 1);
                else         zero_frags(Ah, Al, 3);
            } else {
                uint32_t e = tag_of(t - 1);
                if (kh == 0) spin_frags<1>(hr + 0 + lq * 8, 32, e, &Ah[2], &Al[2]);
                else         spin_frags<3>(hr + 32 + lq * 8, 32, e, Ah, Al);
            }

            f32x4 acc[4];
#pragma unroll
            for (int g = 0; g < 4; g++) acc[g] = (f32x4){0.f, 0.f, 0.f, 0.f};
#pragma unroll
            for (int ktl = 0; ktl < 3; ktl++)
#pragma unroll
                for (int g = 0; g < 4; g++){
                    acc[g] = MFMA(Ah[ktl], wh[g][ktl], acc[g]);
                    acc[g] = MFMA(Ah[ktl], wl[g][ktl], acc[g]);
                    acc[g] = MFMA(Al[ktl], wh[g][ktl], acc[g]);
                }

            if (wave >= 2){
#pragma unroll
                for (int g = 0; g < 4; g++)
                    *(f32x4*)(part + ((wave - 2) * 4 + g) * 256 + lane * 4) = acc[g];
            }
            __syncthreads();
            if (wave < 2){
#pragma unroll
                for (int g = 0; g < 4; g++)
                    acc[g] += *(f32x4*)(part + (wave * 4 + g) * 256 + lane * 4);
                uint32_t* wrow = h0p + ((size_t)(t & 3) * B_ALL + b0 + mt * 16 + lq * 4) * HID
                               + slice * 16 + lm;
                const uint32_t wtag = tag_of(t);
#pragma unroll
                for (int r = 0; r < 4; r++){
                    float zi = acc[0][r] + bias[0], zf = acc[1][r] + bias[1];
                    float zg = acc[2][r] + bias[2], zo = acc[3][r] + bias[3];
                    float cn = sigm(zf) * cst[r] + sigm(zi) * tanh_f(zg);
                    float hn = sigm(zo) * tanh_f(cn);
                    cst[r] = cn;
                    unsigned short hh, ll; split_pair(hn, hh, ll);
                    h_store(wrow + (size_t)r * HID,
                            ((uint32_t)hh << 16) | ((uint32_t)(ll & 0xfffcu)) | wtag);
                }
                // no drain, no forward watermark: tags carry readiness
            }
        }
    } else {
        // ---- layer 1: gates = h0(t) @ Wih1^T + h1(t-1) @ Whh1^T; + action(t-1) ----
        // K = 128 (h0: kt 0..3) + 128 (h1: kt 4..7); kh=0 -> h0 half, kh=1 -> h1 half
        s16x8 wh[4][4], wl[4][4];
#pragma unroll
        for (int g = 0; g < 4; g++)
#pragma unroll
            for (int ktl = 0; ktl < 4; ktl++){
                int kt = kh * 4 + ktl;
                int j = g * HID + slice * 16 + lm;
                const float* src = (kt < 4) ? (Wih1 + (size_t)j * HID + kt * 32 + lq * 8)
                                            : (Whh1 + (size_t)j * HID + (kt - 4) * 32 + lq * 8);
                load_split8(src, wh[g][ktl], wl[g][ktl]);
            }
        float bias[4];
#pragma unroll
        for (int g = 0; g < 4; g++){
            int j = g * HID + slice * 16 + lm;
            bias[g] = bih1[j] + bhh1[j];
        }
        float cst[4] = {0.f, 0.f, 0.f, 0.f};

        s16x8 oh[4], ol[4];
        float ob = 0.f;
#pragma unroll
        for (int ktl = 0; ktl < 4; ktl++)
#pragma unroll
            for (int i = 0; i < 8; i++){ oh[ktl][i] = 0; ol[ktl][i] = 0; }
        if (kh == 1 && lm < ADIM){
#pragma unroll
            for (int ktl = 0; ktl < 4; ktl++)
                load_split8(Wout + (size_t)lm * HID + ktl * 32 + lq * 8, oh[ktl], ol[ktl]);
            ob = bout[lm];
        }

        for (int t = 0; t < T_STEPS; t++){
            s16x8 Ah[4], Al[4];
            if (kh == 0){
                // forward edge: spin on h0(t) tags directly
                const uint32_t* hr = h0p + ((size_t)(t & 3) * B_ALL + b0 + mt * 16 + lm) * HID;
                spin_frags<4>(hr + lq * 8, 32, tag_of(t), Ah, Al);
            } else {
                if (t == 0){
                    zero_frags(Ah, Al, 4);
                } else {
                    const uint32_t* hr = h1p + ((size_t)((t - 1) & 3) * B_ALL + b0 + mt * 16 + lm) * HID;
                    spin_frags<4>(hr + lq * 8, 32, tag_of(t - 1), Ah, Al);
                }
            }

            f32x4 acc[4];
#pragma unroll
            for (int g = 0; g < 4; g++) acc[g] = (f32x4){0.f, 0.f, 0.f, 0.f};
#pragma unroll
            for (int ktl = 0; ktl < 4; ktl++)
#pragma unroll
                for (int g = 0; g < 4; g++){
                    acc[g] = MFMA(Ah[ktl], wh[g][ktl], acc[g]);
                    acc[g] = MFMA(Ah[ktl], wl[g][ktl], acc[g]);
                    acc[g] = MFMA(Al[ktl], wh[g][ktl], acc[g]);
                }

            if (wave >= 2){
#pragma unroll
                for (int g = 0; g < 4; g++)
                    *(f32x4*)(part + ((wave - 2) * 4 + g) * 256 + lane * 4) = acc[g];
            }
            __syncthreads();
            if (wave < 2){
#pragma unroll
                for (int g = 0; g < 4; g++)
                    acc[g] += *(f32x4*)(part + (wave * 4 + g) * 256 + lane * 4);
                uint32_t* wrow = h1p + ((size_t)(t & 3) * B_ALL + b0 + mt * 16 + lq * 4) * HID
                               + slice * 16 + lm;
                const uint32_t wtag = tag_of(t);
#pragma unroll
                for (int r = 0; r < 4; r++){
                    float zi = acc[0][r] + bias[0], zf = acc[1][r] + bias[1];
                    float zg = acc[2][r] + bias[2], zo = acc[3][r] + bias[3];
                    float cn = sigm(zf) * cst[r] + sigm(zi) * tanh_f(zg);
                    float hn = sigm(zo) * tanh_f(cn);
                    cst[r] = cn;
                    unsigned short hh, ll; split_pair(hn, hh, ll);
                    h_store(wrow + (size_t)r * HID,
                            ((uint32_t)hh << 16) | ((uint32_t)(ll & 0xfffcu)) | wtag);
                }
                // read-progress watermark (anti-dep for layer-0): relaxed, no drain.
                // Publishing t+1 certifies this WG's reads of h0(t)/h1(t-1) completed
                // (they fed the MFMAs above in program order).
                if (lane == 0) wm_publish_nd(wm1, slice * 2 + mt, (uint32_t)(t + 1));
            } else if (t > 0){
                // action(t-1) = tanh(h1(t-1) @ Wout^T + bout): reuse h1 frags in regs
                f32x4 oacc = (f32x4){0.f, 0.f, 0.f, 0.f};
#pragma unroll
                for (int ktl = 0; ktl < 4; ktl++){
                    oacc = MFMA(Ah[ktl], oh[ktl], oacc);
                    oacc = MFMA(Ah[ktl], ol[ktl], oacc);
                    oacc = MFMA(Al[ktl], oh[ktl], oacc);
                }
                if (lm < ADIM){
#pragma unroll
                    for (int r = 0; r < 4; r++){
                        int b = b0 + mt * 16 + lq * 4 + r;
                        out[((size_t)(t - 1) * B_ALL + b) * ADIM + lm] = tanh_f(oacc[r] + ob);
                    }
                }
            }
        }
        // epilogue: action(511) from h1(511) (slot 511&3 = 3, tag_of(511)=0;
        // prior content of slot 3 was h1(507) with tag 3 — distinguishable)
        if (kh == 1){
            const uint32_t* hr = h1p + ((size_t)3 * B_ALL + b0 + mt * 16 + lm) * HID;
            s16x8 Ah[4], Al[4];
            spin_frags<4>(hr + lq * 8, 32, tag_of(T_STEPS - 1), Ah, Al);
            f32x4 oacc = (f32x4){0.f, 0.f, 0.f, 0.f};
#pragma unroll
            for (int ktl = 0; ktl < 4; ktl++){
                oacc = MFMA(Ah[ktl], oh[ktl], oacc);
                oacc = MFMA(Ah[ktl], ol[ktl], oacc);
                oacc = MFMA(Al[ktl], oh[ktl], oacc);
            }
            if (lm < ADIM){
#pragma unroll
                for (int r = 0; r < 4; r++){
                    int b = b0 + mt * 16 + lq * 4 + r;
                    out[((size_t)(T_STEPS - 1) * B_ALL + b) * ADIM + lm] = tanh_f(oacc[r] + ob);
                }
            }
        }
    }
}

extern "C" void kernel_launch(void* const* d_in, const int* in_sizes, int n_in,
                              void* d_out, int out_size, void* d_ws, size_t ws_size,
                              hipStream_t stream)
{
    (void)in_sizes; (void)n_in; (void)out_size; (void)ws_size;
    const float* x    = (const float*)d_in[0];
    const float* Wih0 = (const float*)d_in[1];
    const float* Whh0 = (const float*)d_in[2];
    const float* bih0 = (const float*)d_in[3];
    const float* bhh0 = (const float*)d_in[4];
    const float* Wih1 = (const float*)d_in[5];
    const float* Whh1 = (const float*)d_in[6];
    const float* bih1 = (const float*)d_in[7];
    const float* bhh1 = (const float*)d_in[8];
    const float* Wout = (const float*)d_in[9];
    const float* bout = (const float*)d_in[10];

    // ws: [0,16KB) wm1 (16 chunks x 16 slots x 64B),
    //     [16KB, ...) h0/h1 packed (hi|lo|tag2) u32 buffers, NSLOT slots each
    const size_t ws_used = 16384 + 2 * (size_t)NSLOT * B_ALL * HID * sizeof(uint32_t); // ~2.1 MB
    hipMemsetAsync(d_ws, 0, ws_used, stream);

    const size_t lds_bytes = 8 * 256 * sizeof(float);   // 8 KB partial-sum buffer
    hipLaunchKernelGGL(lstm_fused, dim3(256), dim3(256), lds_bytes, stream,
                       x, Wih0, Whh0, bih0, bhh0, Wih1, Whh1, bih1, bhh1, Wout, bout,
                       (float*)d_out, (unsigned char*)d_ws);
}

// Round 10
// 1633.615 us; speedup vs baseline: 1.4857x; 1.4857x over previous
//
#include <hip/hip_runtime.h>
#include <stdint.h>

#define T_STEPS 512
#define B_ALL   512
#define SDIM    64
#define HID     128
#define ADIM    10
#define CB      16      // batch rows per chunk (one full MFMA row-tile)
#define NCH     32      // chunks
#define LROW    17      // transposed h-LDS pad (u32 words per unit row)
#define SROW    129     // A-stage LDS row pad
#define WPAD    132     // Wout LDS row pad

typedef __attribute__((ext_vector_type(4))) float f32x4;
typedef __attribute__((ext_vector_type(8))) short s16x8;

#define MFMA(a,b,c) __builtin_amdgcn_mfma_f32_16x16x32_bf16(a,b,c,0,0,0)
#define SC_AGENT __HIP_MEMORY_SCOPE_AGENT

__device__ __forceinline__ unsigned short bf_rne(float f){
    union{float f; unsigned int u;} v; v.f = f;
    unsigned int r = v.u + 0x7fffu + ((v.u >> 16) & 1u);
    return (unsigned short)(r >> 16);
}
__device__ __forceinline__ float us_to_f(unsigned short h){
    union{unsigned int u; float f;} v; v.u = ((unsigned int)h) << 16; return v.f;
}
__device__ __forceinline__ void split_pair(float f, unsigned short& hi, unsigned short& lo){
    hi = bf_rne(f);
    lo = bf_rne(f - us_to_f(hi));
}
__device__ __forceinline__ void load_split8(const float* p, s16x8& h, s16x8& l){
#pragma unroll
    for (int i = 0; i < 8; i++){
        unsigned short a, b; split_pair(p[i], a, b);
        h[i] = (short)a; l[i] = (short)b;
    }
}
__device__ __forceinline__ float sigm(float x){ return 1.f / (1.f + __expf(-x)); }
__device__ __forceinline__ float tanh_f(float x){ return 1.f - 2.f / (__expf(2.f * x) + 1.f); }

// ---- K-split pipeline: 4 roles per chunk, each on its own CU ----
//   X : xpart(t) = x(t)@Wih0^T            -> xring   (no deps, runs ahead)
//   R0: xpart + h0(t-1)@Whh0^T -> h0(t);  h0 recurrence in LDS; h0 -> hring
//   A : pA(t) = h0(t)@Wih1^T              -> aring   (forward, constant lag)
//   R1: pA + h1(t-1)@Whh1^T -> h1(t);     h1 recurrence in LDS; action in-CU
// Rings are self-tagged per word (2-bit epoch in fp32-mantissa / lo-bf16 LSBs,
// tag = ((t>>dsh)+1)&3, 0 = never-written). 4B stores are atomic: no torn
// words, no drains, no separate publish. Backpressure: each consumer publishes
// "steps < t consumed" (plain relaxed word) at the TOP of step t (after its
// step t-1 barrier -> certifies ALL waves). Producer of slot t waits
// prog >= t-(D-1). Depth D = 4/2/1 by available ws.
__device__ __forceinline__ uint32_t ep_tag(int t, int dsh){
    return (uint32_t)(((t >> dsh) + 1) & 3);
}
__device__ __forceinline__ void wait_word(const uint32_t* p, uint32_t v, uint32_t& seen){
    if (seen >= v) return;
    uint32_t c;
    while ((c = __hip_atomic_load(p, __ATOMIC_RELAXED, SC_AGENT)) < v)
        __builtin_amdgcn_s_sleep(1);
    seen = c;
    __asm__ volatile("" ::: "memory");
}
// lane's base index into a 32KB fp32 gates slot: [(w*4+lq)*64 + lm*4] (+r)
__device__ __forceinline__ int gidx(int w, int lq, int lm){ return (w * 4 + lq) * 64 + lm * 4; }

__device__ __forceinline__ void ring_load16(const float* slot, int i0, unsigned long long* pw){
#pragma unroll
    for (int g = 0; g < 4; g++){
        const unsigned long long* p = (const unsigned long long*)(slot + g * 2048 + i0);
        pw[g * 2]     = __hip_atomic_load(p,     __ATOMIC_RELAXED, SC_AGENT);
        pw[g * 2 + 1] = __hip_atomic_load(p + 1, __ATOMIC_RELAXED, SC_AGENT);
    }
}
__device__ __forceinline__ uint32_t tags_bad16(const unsigned long long* pw, uint32_t e){
    uint32_t bad = 0;
#pragma unroll
    for (int k = 0; k < 8; k++){
        uint32_t a = (uint32_t)pw[k], b = (uint32_t)(pw[k] >> 32);
        bad |= ((a ^ e) & 3u) | ((b ^ e) & 3u);
    }
    return bad;
}
__device__ __forceinline__ void pub_f4(float* dst, f32x4 v, uint32_t e){
    uint32_t q0 = (__float_as_uint(v[0]) & ~3u) | e;
    uint32_t q1 = (__float_as_uint(v[1]) & ~3u) | e;
    uint32_t q2 = (__float_as_uint(v[2]) & ~3u) | e;
    uint32_t q3 = (__float_as_uint(v[3]) & ~3u) | e;
    __hip_atomic_store((unsigned long long*)dst,
        ((unsigned long long)q1 << 32) | q0, __ATOMIC_RELAXED, SC_AGENT);
    __hip_atomic_store((unsigned long long*)dst + 1,
        ((unsigned long long)q3 << 32) | q2, __ATOMIC_RELAXED, SC_AGENT);
}

__global__ void __launch_bounds__(512, 2)
lstm_pipe(const float* __restrict__ x,
          const float* __restrict__ Wih0, const float* __restrict__ Whh0,
          const float* __restrict__ bih0, const float* __restrict__ bhh0,
          const float* __restrict__ Wih1, const float* __restrict__ Whh1,
          const float* __restrict__ bih1, const float* __restrict__ bhh1,
          const float* __restrict__ Wout, const float* __restrict__ bout,
          float* __restrict__ out, unsigned char* __restrict__ ws, int dsh)
{
    extern __shared__ uint32_t lds[];
    // R roles: hbuf [2][128][LROW] (17408B) + R1: wlds [16][WPAD] (8448B)
    // A role : stage [2][16][SROW] (16512B)

    const int tid  = threadIdx.x;
    const int wave = tid >> 6, lane = tid & 63;
    const int lm = lane & 15, lq = lane >> 4;
    const int w  = wave;                       // hidden-block 0..7 (16 units each)

    const int c    = blockIdx.x >> 2;
    const int role = blockIdx.x & 3;           // 0=X 1=A 2=R0 3=R1
    const int b0   = c * CB;

    const int D = 1 << dsh, dmask = D - 1;

    uint32_t* prog = (uint32_t*)(ws + (size_t)c * 512);
    // prog[0]=r0prog (xring consumed), prog[32]=aprog (hring consumed),
    // prog[64]=r1prog (aring consumed)
    unsigned char* rb = ws + 16384;
    float*    xring = (float*)rb + (size_t)c * D * 8192;
    float*    aring = (float*)(rb + (size_t)NCH * D * 32768) + (size_t)c * D * 8192;
    uint32_t* hring = (uint32_t*)(rb + (size_t)2 * NCH * D * 32768) + (size_t)c * D * 2048;

    if (role == 0){
        // ================= X: xpart(t) = x(t) @ Wih0^T =================
        s16x8 wh[4][2], wl[4][2];
#pragma unroll
        for (int g = 0; g < 4; g++)
#pragma unroll
            for (int kt = 0; kt < 2; kt++){
                int j = g * HID + w * 16 + lm;
                load_split8(Wih0 + (size_t)j * SDIM + kt * 32 + lq * 8, wh[g][kt], wl[g][kt]);
            }
        uint32_t seen = 0;
        for (int t = 0; t < T_STEPS; t++){
            const float* xp = x + ((size_t)t * B_ALL + b0 + lm) * SDIM;
            s16x8 Ah[2], Al[2];
#pragma unroll
            for (int kt = 0; kt < 2; kt++)
#pragma unroll
                for (int j = 0; j < 8; j++){
                    unsigned short hh, ll; split_pair(xp[kt * 32 + lq * 8 + j], hh, ll);
                    Ah[kt][j] = (short)hh; Al[kt][j] = (short)ll;
                }
            f32x4 acc[4];
#pragma unroll
            for (int g = 0; g < 4; g++) acc[g] = (f32x4){0.f, 0.f, 0.f, 0.f};
#pragma unroll
            for (int kt = 0; kt < 2; kt++)
#pragma unroll
                for (int g = 0; g < 4; g++){
                    acc[g] = MFMA(Ah[kt], wh[g][kt], acc[g]);
                    acc[g] = MFMA(Ah[kt], wl[g][kt], acc[g]);
                    acc[g] = MFMA(Al[kt], wh[g][kt], acc[g]);
                }
            if (t >= D) wait_word(prog + 0, (uint32_t)(t - (D - 1)), seen);
            float* slot = xring + (size_t)(t & dmask) * 8192;
            uint32_t e = ep_tag(t, dsh);
#pragma unroll
            for (int g = 0; g < 4; g++)
                pub_f4(slot + g * 2048 + gidx(w, lq, lm), acc[g], e);
        }
    } else if (role == 1){
        // ================= A: pA(t) = h0(t) @ Wih1^T =================
        uint32_t* stage = lds;                       // [2][16][SROW]
        s16x8 wh[4][4], wl[4][4];
#pragma unroll
        for (int g = 0; g < 4; g++)
#pragma unroll
            for (int kt = 0; kt < 4; kt++){
                int j = g * HID + w * 16 + lm;
                load_split8(Wih1 + (size_t)j * HID + kt * 32 + lq * 8, wh[g][kt], wl[g][kt]);
            }
        uint32_t seenR1 = 0;
        // per-wave hring stake: rows 2w, 2w+1 (batch), lane covers 4 unit-cols
        const int srow = 2 * w + (lane >> 5);
        const int scol = (lane & 31) * 4;
        unsigned long long hw[2];
        {
            const unsigned long long* p =
                (const unsigned long long*)(hring + srow * 128 + scol);
            hw[0] = __hip_atomic_load(p,     __ATOMIC_RELAXED, SC_AGENT);
            hw[1] = __hip_atomic_load(p + 1, __ATOMIC_RELAXED, SC_AGENT);
        }
        for (int t = 0; t < T_STEPS; t++){
            if (t && w == 0 && lane == 0)
                __hip_atomic_store(prog + 32, (uint32_t)t, __ATOMIC_RELAXED, SC_AGENT);
            uint32_t e = ep_tag(t, dsh);
            const unsigned long long* p =
                (const unsigned long long*)(hring + (size_t)(t & dmask) * 2048 + srow * 128 + scol);
            for (;;){
                uint32_t bad = 0;
#pragma unroll
                for (int k = 0; k < 2; k++){
                    uint32_t a = (uint32_t)hw[k], b = (uint32_t)(hw[k] >> 32);
                    bad |= ((a ^ e) & 3u) | ((b ^ e) & 3u);
                }
                if (__all(bad == 0)) break;
                __builtin_amdgcn_s_sleep(1);
                hw[0] = __hip_atomic_load(p,     __ATOMIC_RELAXED, SC_AGENT);
                hw[1] = __hip_atomic_load(p + 1, __ATOMIC_RELAXED, SC_AGENT);
            }
            uint32_t* sb = stage + (t & 1) * 16 * SROW + srow * SROW + scol;
            sb[0] = (uint32_t)hw[0]; sb[1] = (uint32_t)(hw[0] >> 32);
            sb[2] = (uint32_t)hw[1]; sb[3] = (uint32_t)(hw[1] >> 32);
            __syncthreads();
            if (t < T_STEPS - 1){                    // prefetch next stake
                const unsigned long long* pn =
                    (const unsigned long long*)(hring + (size_t)((t + 1) & dmask) * 2048 + srow * 128 + scol);
                hw[0] = __hip_atomic_load(pn,     __ATOMIC_RELAXED, SC_AGENT);
                hw[1] = __hip_atomic_load(pn + 1, __ATOMIC_RELAXED, SC_AGENT);
            }
            s16x8 Ah[4], Al[4];
            const uint32_t* sr = stage + (t & 1) * 16 * SROW + lm * SROW;
#pragma unroll
            for (int kt = 0; kt < 4; kt++)
#pragma unroll
                for (int j = 0; j < 8; j++){
                    uint32_t v = sr[kt * 32 + lq * 8 + j];
                    Ah[kt][j] = (short)(v >> 16); Al[kt][j] = (short)(v & 0xffffu);
                }
            f32x4 acc[4];
#pragma unroll
            for (int g = 0; g < 4; g++) acc[g] = (f32x4){0.f, 0.f, 0.f, 0.f};
#pragma unroll
            for (int kt = 0; kt < 4; kt++)
#pragma unroll
                for (int g = 0; g < 4; g++){
                    acc[g] = MFMA(Ah[kt], wh[g][kt], acc[g]);
                    acc[g] = MFMA(Ah[kt], wl[g][kt], acc[g]);
                    acc[g] = MFMA(Al[kt], wh[g][kt], acc[g]);
                }
            if (t >= D) wait_word(prog + 64, (uint32_t)(t - (D - 1)), seenR1);
            float* slot = aring + (size_t)(t & dmask) * 8192;
#pragma unroll
            for (int g = 0; g < 4; g++)
                pub_f4(slot + g * 2048 + gidx(w, lq, lm), acc[g], e);
        }
    } else {
        // ============ R0 / R1: recurrent stages, h in LDS, full-K per wave ============
        const bool isR1 = (role == 3);
        uint32_t* hbuf = lds;                        // [2][128][LROW]
        uint32_t* wlds = lds + 2 * 128 * LROW;       // R1: [16][WPAD] packed Wout
        for (int i = tid; i < 2 * 128 * LROW; i += 512) hbuf[i] = 0;
        if (isR1){
            for (int i = tid; i < 16 * 128; i += 512){
                int rrow = i >> 7, k = i & 127;
                uint32_t pk = 0;
                if (rrow < ADIM){
                    unsigned short hh, ll;
                    split_pair(Wout[(size_t)rrow * HID + k], hh, ll);
                    pk = ((uint32_t)hh << 16) | (uint32_t)ll;
                }
                wlds[rrow * WPAD + k] = pk;
            }
        }
        __syncthreads();

        s16x8 wh[4][4], wl[4][4];
        const float* Whh = isR1 ? Whh1 : Whh0;
#pragma unroll
        for (int g = 0; g < 4; g++)
#pragma unroll
            for (int kt = 0; kt < 4; kt++){
                int j = g * HID + w * 16 + lm;
                load_split8(Whh + (size_t)j * HID + kt * 32 + lq * 8, wh[g][kt], wl[g][kt]);
            }
        float bias[4];
#pragma unroll
        for (int g = 0; g < 4; g++){
            int j = g * HID + w * 16 + lm;
            bias[g] = isR1 ? (bih1[j] + bhh1[j]) : (bih0[j] + bhh0[j]);
        }
        float cst[4] = {0.f, 0.f, 0.f, 0.f};
        float ob = (isR1 && lm < ADIM) ? bout[lm] : 0.f;

        const float* inring = isR1 ? aring : xring;
        uint32_t* myprog    = isR1 ? (prog + 64) : (prog + 0);
        uint32_t seenBP = 0;
        const int i0 = gidx(w, lq, lm);

        unsigned long long pw[8];
        ring_load16(inring, i0, pw);                 // prefetch slot 0

        for (int t = 0; t < T_STEPS; t++){
            if (t && w == 0 && lane == 0)
                __hip_atomic_store(myprog, (uint32_t)t, __ATOMIC_RELAXED, SC_AGENT);
            uint32_t e = ep_tag(t, dsh);
            const float* slot = inring + (size_t)(t & dmask) * 8192;
            for (;;){
                if (__all(tags_bad16(pw, e) == 0)) break;
                __builtin_amdgcn_s_sleep(1);
                ring_load16(slot, i0, pw);
            }
            f32x4 acc[4];
#pragma unroll
            for (int g = 0; g < 4; g++){
                acc[g][0] = __uint_as_float((uint32_t)pw[g * 2])             + bias[g];
                acc[g][1] = __uint_as_float((uint32_t)(pw[g * 2] >> 32))     + bias[g];
                acc[g][2] = __uint_as_float((uint32_t)pw[g * 2 + 1])         + bias[g];
                acc[g][3] = __uint_as_float((uint32_t)(pw[g * 2 + 1] >> 32)) + bias[g];
            }
            if (t < T_STEPS - 1)                     // prefetch next slot (hides under MFMAs)
                ring_load16(inring + (size_t)((t + 1) & dmask) * 8192, i0, pw);

            // h(t-1) fragments from LDS (transposed layout, dbuf (t&1)^1)
            s16x8 Ah[4], Al[4];
            const uint32_t* hb = hbuf + ((t & 1) ^ 1) * 128 * LROW;
#pragma unroll
            for (int kt = 0; kt < 4; kt++)
#pragma unroll
                for (int j = 0; j < 8; j++){
                    uint32_t v = hb[(kt * 32 + lq * 8 + j) * LROW + lm];
                    Ah[kt][j] = (short)(v >> 16); Al[kt][j] = (short)(v & 0xffffu);
                }

            // R1: action(t-1) = tanh(h1(t-1)@Wout^T + bout); rotates across waves
            if (isR1 && t > 0 && w == (t & 7)){
                f32x4 oacc = (f32x4){0.f, 0.f, 0.f, 0.f};
#pragma unroll
                for (int kt = 0; kt < 4; kt++){
                    s16x8 oh, ol;
#pragma unroll
                    for (int j = 0; j < 8; j++){
                        uint32_t v = wlds[lm * WPAD + kt * 32 + lq * 8 + j];
                        oh[j] = (short)(v >> 16); ol[j] = (short)(v & 0xffffu);
                    }
                    oacc = MFMA(Ah[kt], oh, oacc);
                    oacc = MFMA(Ah[kt], ol, oacc);
                    oacc = MFMA(Al[kt], oh, oacc);
                }
                if (lm < ADIM){
#pragma unroll
                    for (int r = 0; r < 4; r++)
                        out[((size_t)(t - 1) * B_ALL + b0 + lq * 4 + r) * ADIM + lm] =
                            tanh_f(oacc[r] + ob);
                }
            }

#pragma unroll
            for (int kt = 0; kt < 4; kt++)
#pragma unroll
                for (int g = 0; g < 4; g++){
                    acc[g] = MFMA(Ah[kt], wh[g][kt], acc[g]);
                    acc[g] = MFMA(Ah[kt], wl[g][kt], acc[g]);
                    acc[g] = MFMA(Al[kt], wh[g][kt], acc[g]);
                }

            if (!isR1 && t >= D)                     // hring anti-dep: A consumed h0(t-D)
                wait_word(prog + 32, (uint32_t)(t - (D - 1)), seenBP);

            uint32_t* lb = hbuf + (t & 1) * 128 * LROW + (w * 16 + lm) * LROW + lq * 4;
            uint32_t* hdst = hring + (size_t)(t & dmask) * 2048;
#pragma unroll
            for (int r = 0; r < 4; r++){
                float zi = acc[0][r], zf = acc[1][r], zg = acc[2][r], zo = acc[3][r];
                float cn = sigm(zf) * cst[r] + sigm(zi) * tanh_f(zg);
                float hn = sigm(zo) * tanh_f(cn);
                cst[r] = cn;
                unsigned short hh, ll; split_pair(hn, hh, ll);
                lb[r] = ((uint32_t)hh << 16) | (uint32_t)ll;
                if (!isR1)
                    __hip_atomic_store(hdst + (size_t)(lq * 4 + r) * 128 + w * 16 + lm,
                                       ((uint32_t)hh << 16) | ((uint32_t)(ll & 0xfffcu)) | e,
                                       __ATOMIC_RELAXED, SC_AGENT);
            }
            __syncthreads();
        }
        // R1 epilogue: action(511) from h1(511) in LDS buf[(511)&1]=1
        if (isR1 && w == 0){
            s16x8 Ah[4], Al[4];
            const uint32_t* hb = hbuf + ((T_STEPS - 1) & 1) * 128 * LROW;
#pragma unroll
            for (int kt = 0; kt < 4; kt++)
#pragma unroll
                for (int j = 0; j < 8; j++){
                    uint32_t v = hb[(kt * 32 + lq * 8 + j) * LROW + lm];
                    Ah[kt][j] = (short)(v >> 16); Al[kt][j] = (short)(v & 0xffffu);
                }
            f32x4 oacc = (f32x4){0.f, 0.f, 0.f, 0.f};
#pragma unroll
            for (int kt = 0; kt < 4; kt++){
                s16x8 oh, ol;
#pragma unroll
                for (int j = 0; j < 8; j++){
                    uint32_t v = wlds[lm * WPAD + kt * 32 + lq * 8 + j];
                    oh[j] = (short)(v >> 16); ol[j] = (short)(v & 0xffffu);
                }
                oacc = MFMA(Ah[kt], oh, oacc);
                oacc = MFMA(Ah[kt], ol, oacc);
                oacc = MFMA(Al[kt], oh, oacc);
            }
            if (lm < ADIM){
#pragma unroll
                for (int r = 0; r < 4; r++)
                    out[((size_t)(T_STEPS - 1) * B_ALL + b0 + lq * 4 + r) * ADIM + lm] =
                        tanh_f(oacc[r] + ob);
            }
        }
    }
}

extern "C" void kernel_launch(void* const* d_in, const int* in_sizes, int n_in,
                              void* d_out, int out_size, void* d_ws, size_t ws_size,
                              hipStream_t stream)
{
    (void)in_sizes; (void)n_in; (void)out_size;
    const float* x    = (const float*)d_in[0];
    const float* Wih0 = (const float*)d_in[1];
    const float* Whh0 = (const float*)d_in[2];
    const float* bih0 = (const float*)d_in[3];
    const float* bhh0 = (const float*)d_in[4];
    const float* Wih1 = (const float*)d_in[5];
    const float* Whh1 = (const float*)d_in[6];
    const float* bih1 = (const float*)d_in[7];
    const float* bhh1 = (const float*)d_in[8];
    const float* Wout = (const float*)d_in[9];
    const float* bout = (const float*)d_in[10];

    // ws: [0,16KB) progress words (32 chunks x 512B),
    //     [16KB,...) xring | aring | hring, each NCH * D slots
    auto need = [](int dsh){ size_t D = (size_t)1 << dsh;
                             return (size_t)16384 + (size_t)NCH * D * (2 * 32768 + 8192); };
    int dsh = 2;
    if (ws_size && ws_size < need(2)) dsh = 1;
    if (ws_size && ws_size < need(1)) dsh = 0;
    hipMemsetAsync(d_ws, 0, need(dsh), stream);

    const size_t lds_bytes = (2 * 128 * LROW + 16 * WPAD) * sizeof(uint32_t);  // 25856 B
    hipLaunchKernelGGL(lstm_pipe, dim3(NCH * 4), dim3(512), lds_bytes, stream,
                       x, Wih0, Whh0, bih0, bhh0, Wih1, Whh1, bih1, bhh1, Wout, bout,
                       (float*)d_out, (unsigned char*)d_ws, dsh);
}